// Round 8
// baseline (232.018 us; speedup 1.0000x reference)
//
#include <hip/hip_runtime.h>
#include <hip/hip_bf16.h>
#include <type_traits>

typedef __attribute__((ext_vector_type(8))) short bf16x8;
typedef __attribute__((ext_vector_type(4))) float floatx4;
typedef __attribute__((ext_vector_type(2))) float float2v;

__device__ __forceinline__ float bf2f(unsigned short u) {
    union { unsigned int x; float f; } v; v.x = ((unsigned int)u) << 16; return v.f;
}
__device__ __forceinline__ unsigned short f2bf(float f) {
    union { float f; unsigned int u; } v; v.f = f;
    unsigned int x = v.u;
    unsigned int r = x + 0x7fffu + ((x >> 16) & 1u);
    return (unsigned short)(r >> 16);
}

// async global->LDS, 16B per lane; lds base must be wave-uniform (HW adds lane*16)
typedef const __attribute__((address_space(1))) unsigned int u32_g;
typedef __attribute__((address_space(3))) unsigned int u32_l;
__device__ __forceinline__ void gld_lds16(const void* g, void* l) {
    __builtin_amdgcn_global_load_lds((u32_g*)g, (u32_l*)l, 16, 0, 0);
}

// ---------------------------------------------------------------------------
// prep: fused  x->bf16 convert  +  w_qkv^T->bf16  +  w_proj^T->bf16
// ---------------------------------------------------------------------------
__device__ __forceinline__ void trans32(const float* __restrict__ in,
                                        unsigned short* __restrict__ out,
                                        int K, int N, int bx, int by,
                                        unsigned short (*T)[33]) {
    const int n0 = bx * 32, k0 = by * 32;
    const int r = threadIdx.x >> 3;
    const int c4 = (threadIdx.x & 7) * 4;
    float4 v = *reinterpret_cast<const float4*>(in + (size_t)(k0 + r) * N + n0 + c4);
    T[c4 + 0][r] = f2bf(v.x);
    T[c4 + 1][r] = f2bf(v.y);
    T[c4 + 2][r] = f2bf(v.z);
    T[c4 + 3][r] = f2bf(v.w);
    __syncthreads();
    ushort4 o = {T[r][c4], T[r][c4 + 1], T[r][c4 + 2], T[r][c4 + 3]};
    *reinterpret_cast<ushort4*>(out + (size_t)(n0 + r) * K + k0 + c4) = o;
}

__global__ __launch_bounds__(256) void prep(const float* __restrict__ x,
                                            unsigned short* __restrict__ xb,
                                            const float* __restrict__ wq,
                                            unsigned short* __restrict__ wqT,
                                            const float* __restrict__ wp,
                                            unsigned short* __restrict__ wpT) {
    __shared__ unsigned short T[32][33];
    const int b = blockIdx.x;
    if (b < 1024) {
        size_t i = ((size_t)b * 256 + threadIdx.x) * 8;
        float4 a = *reinterpret_cast<const float4*>(x + i);
        float4 c = *reinterpret_cast<const float4*>(x + i + 4);
        unsigned short t[8] = {f2bf(a.x), f2bf(a.y), f2bf(a.z), f2bf(a.w),
                               f2bf(c.x), f2bf(c.y), f2bf(c.z), f2bf(c.w)};
        *reinterpret_cast<uint4*>(xb + i) = *reinterpret_cast<const uint4*>(t);
    } else if (b < 4096) {
        int t = b - 1024;
        trans32(wq, wqT, 1024, 3072, t % 96, t / 96, T);
    } else {
        int t = b - 4096;
        trans32(wp, wpT, 1024, 1024, t % 32, t / 32, T);
    }
}

// ---------------------------------------------------------------------------
// m97-style GEMM, 128x128 tile, BK=32: C = A[M,K] * Bt[N,K]^T, bf16->bf16.
// 4 waves; wave (wm,wn) computes 64x64 via 16 MFMA per K-iter.
// ---------------------------------------------------------------------------
__global__ __launch_bounds__(256) void gemm128(const unsigned short* __restrict__ A,
                                               const unsigned short* __restrict__ Bt,
                                               unsigned short* __restrict__ C,
                                               int M, int N, int K) {
    __shared__ __align__(16) unsigned short As[128 * 32];
    __shared__ __align__(16) unsigned short Bs[128 * 32];

    const int tid = threadIdx.x;
    const int wave = tid >> 6;
    const int lane = tid & 63;
    const int m15 = lane & 15;
    const int quad = lane >> 4;
    const int wm = wave >> 1;
    const int wn = wave & 1;
    const int m0 = blockIdx.y * 128;
    const int n0 = blockIdx.x * 128;

    const int srow = lane >> 2;
    const int scol = (lane & 3) * 8;

    floatx4 acc[4][4];
#pragma unroll
    for (int mt = 0; mt < 4; mt++)
#pragma unroll
        for (int nt = 0; nt < 4; nt++) acc[mt][nt] = {0.f, 0.f, 0.f, 0.f};

    for (int k0 = 0; k0 < K; k0 += 32) {
#pragma unroll
        for (int i = 0; i < 2; i++) {
            int j = wave * 2 + i;
            gld_lds16(A + (size_t)(m0 + j * 16 + srow) * K + k0 + scol, &As[j * 16 * 32]);
            gld_lds16(Bt + (size_t)(n0 + j * 16 + srow) * K + k0 + scol, &Bs[j * 16 * 32]);
        }
        __syncthreads();

        bf16x8 a[4];
#pragma unroll
        for (int mt = 0; mt < 4; mt++)
            a[mt] = *reinterpret_cast<bf16x8*>(&As[(wm * 64 + mt * 16 + m15) * 32 + quad * 8]);
#pragma unroll
        for (int nt = 0; nt < 4; nt++) {
            bf16x8 b = *reinterpret_cast<bf16x8*>(&Bs[(wn * 64 + nt * 16 + m15) * 32 + quad * 8]);
#pragma unroll
            for (int mt = 0; mt < 4; mt++)
                acc[mt][nt] = __builtin_amdgcn_mfma_f32_16x16x32_bf16(a[mt], b, acc[mt][nt], 0, 0, 0);
        }
        __syncthreads();
    }

#pragma unroll
    for (int mt = 0; mt < 4; mt++)
#pragma unroll
        for (int nt = 0; nt < 4; nt++)
#pragma unroll
            for (int i = 0; i < 4; i++) {
                int row = m0 + wm * 64 + mt * 16 + quad * 4 + i;
                int col = n0 + wn * 64 + nt * 16 + m15;
                C[(size_t)row * N + col] = f2bf(acc[mt][nt][i]);
            }
}

// ---------------------------------------------------------------------------
// GEMM: BM=64 (used for proj). C fp32 out.
// ---------------------------------------------------------------------------
template<int BN, typename TC>
__global__ __launch_bounds__(256) void gemm_abt(const unsigned short* __restrict__ A,
                                                const unsigned short* __restrict__ Bt,
                                                TC* __restrict__ C,
                                                int M, int N, int K) {
    constexpr int NT = BN / 32;
    __shared__ __align__(16) unsigned short As[64 * 32];
    __shared__ __align__(16) unsigned short Bs[BN * 32];

    const int tid = threadIdx.x;
    const int wave = tid >> 6;
    const int lane = tid & 63;
    const int m15 = lane & 15;
    const int quad = lane >> 4;
    const int wm = wave >> 1;
    const int wn = wave & 1;
    const int m0 = blockIdx.y * 64;
    const int n0 = blockIdx.x * BN;

    const int srow = lane >> 2;
    const int scol = (lane & 3) * 8;

    floatx4 acc[2][NT];
#pragma unroll
    for (int mt = 0; mt < 2; mt++)
#pragma unroll
        for (int nt = 0; nt < NT; nt++) acc[mt][nt] = {0.f, 0.f, 0.f, 0.f};

    for (int k0 = 0; k0 < K; k0 += 32) {
        gld_lds16(A + (size_t)(m0 + wave * 16 + srow) * K + k0 + scol, &As[wave * 16 * 32]);
#pragma unroll
        for (int i = 0; i < BN / 64; i++) {
            int j = wave * (BN / 64) + i;
            gld_lds16(Bt + (size_t)(n0 + j * 16 + srow) * K + k0 + scol, &Bs[j * 16 * 32]);
        }
        __syncthreads();

        bf16x8 a[2];
#pragma unroll
        for (int mt = 0; mt < 2; mt++)
            a[mt] = *reinterpret_cast<bf16x8*>(&As[(wm * 32 + mt * 16 + m15) * 32 + quad * 8]);
#pragma unroll
        for (int nt = 0; nt < NT; nt++) {
            bf16x8 b = *reinterpret_cast<bf16x8*>(&Bs[(wn * (BN / 2) + nt * 16 + m15) * 32 + quad * 8]);
#pragma unroll
            for (int mt = 0; mt < 2; mt++)
                acc[mt][nt] = __builtin_amdgcn_mfma_f32_16x16x32_bf16(a[mt], b, acc[mt][nt], 0, 0, 0);
        }
        __syncthreads();
    }

#pragma unroll
    for (int mt = 0; mt < 2; mt++)
#pragma unroll
        for (int nt = 0; nt < NT; nt++)
#pragma unroll
            for (int i = 0; i < 4; i++) {
                int row = m0 + wm * 32 + mt * 16 + quad * 4 + i;
                int col = n0 + wn * (BN / 2) + nt * 16 + m15;
                if constexpr (std::is_same<TC, float>::value)
                    C[(size_t)row * N + col] = acc[mt][nt][i];
                else
                    C[(size_t)row * N + col] = f2bf(acc[mt][nt][i]);
            }
}

// ---------------------------------------------------------------------------
// RelPosBias MLP, operand-swapped MFMA, zero LDS (round-7 structure).
// NOTE: biasb is stored SWIZZLED within each 64-col group:
//   stored_idx = row*2048 + (col & ~63) + (col & 15)*4 + ((col >> 4) & 3)
// so attn can read 4 nt-values per row as one contiguous ushort4.
// Output = (mlp(rel)+b3)*log2(e) as bf16.
// ---------------------------------------------------------------------------
__global__ __launch_bounds__(256) void rpb_mfma_kernel(const float* __restrict__ rel,
                                                       const float* __restrict__ w1,
                                                       const float* __restrict__ b1,
                                                       const float* __restrict__ w2,
                                                       const float* __restrict__ b2,
                                                       const float* __restrict__ w3,
                                                       const float* __restrict__ b3,
                                                       unsigned short* __restrict__ biasb) {
    const int tid = threadIdx.x;
    const int wave = tid >> 6;
    const int lane = tid & 63;
    const int m15 = lane & 15;
    const int quad = lane >> 4;

    bf16x8 af0, af1;
    {
        unsigned short t0[8], t1[8];
#pragma unroll
        for (int j = 0; j < 8; j++) {
            int k = quad * 8 + j;
            t0[j] = f2bf(w2[k * 32 + m15]);
            t1[j] = f2bf(w2[k * 32 + 16 + m15]);
        }
        af0 = *reinterpret_cast<bf16x8*>(t0);
        af1 = *reinterpret_cast<bf16x8*>(t1);
    }

    float2v w1a2[4], w1b2[4], b12[4];
#pragma unroll
    for (int p = 0; p < 4; p++) {
        int base = quad * 8 + 2 * p;
        w1a2[p] = {w1[base], w1[base + 1]};
        w1b2[p] = {w1[32 + base], w1[32 + base + 1]};
        b12[p]  = {b1[base], b1[base + 1]};
    }

    floatx4 b2r0, b2r1;
    float2v w3p00, w3p01, w3p10, w3p11;
    const float LOG2E = 1.44269504f;
    {
        float4 t0 = *reinterpret_cast<const float4*>(b2 + quad * 4);
        float4 t1 = *reinterpret_cast<const float4*>(b2 + 16 + quad * 4);
        b2r0 = {t0.x, t0.y, t0.z, t0.w};
        b2r1 = {t1.x, t1.y, t1.z, t1.w};
        float4 u0 = *reinterpret_cast<const float4*>(w3 + quad * 4);
        float4 u1 = *reinterpret_cast<const float4*>(w3 + 16 + quad * 4);
        w3p00 = {u0.x * LOG2E, u0.y * LOG2E};
        w3p01 = {u0.z * LOG2E, u0.w * LOG2E};
        w3p10 = {u1.x * LOG2E, u1.y * LOG2E};
        w3p11 = {u1.z * LOG2E, u1.w * LOG2E};
    }
    const float b3s = b3[0] * LOG2E;
    const float2v z2 = {0.f, 0.f};

    const int base = blockIdx.x * 1024 + wave * 64;

    for (int it = 0; it < 4; ++it) {
        const int pix0 = base + it * 256;
#pragma unroll
        for (int t = 0; t < 4; t++) {
            const int px = pix0 + t * 16;
            float2 dxy = *reinterpret_cast<const float2*>(rel + (size_t)(px + m15) * 2);
            float2v dx2 = {dxy.x, dxy.x}, dy2 = {dxy.y, dxy.y};

            unsigned int hp[4];
#pragma unroll
            for (int p = 0; p < 4; p++) {
                float2v h = __builtin_elementwise_fma(dx2, w1a2[p],
                             __builtin_elementwise_fma(dy2, w1b2[p], b12[p]));
                h = __builtin_elementwise_max(h, z2);
                hp[p] = __builtin_amdgcn_perm(__float_as_uint(h.y), __float_as_uint(h.x), 0x07060302u);
            }
            bf16x8 hb = *reinterpret_cast<bf16x8*>(hp);

            floatx4 d0 = __builtin_amdgcn_mfma_f32_16x16x32_bf16(af0, hb, b2r0, 0, 0, 0);
            floatx4 d1 = __builtin_amdgcn_mfma_f32_16x16x32_bf16(af1, hb, b2r1, 0, 0, 0);

            float2v m00 = __builtin_elementwise_max(__builtin_shufflevector(d0, d0, 0, 1), z2);
            float2v m01 = __builtin_elementwise_max(__builtin_shufflevector(d0, d0, 2, 3), z2);
            float2v m10 = __builtin_elementwise_max(__builtin_shufflevector(d1, d1, 0, 1), z2);
            float2v m11 = __builtin_elementwise_max(__builtin_shufflevector(d1, d1, 2, 3), z2);
            float2v acc2 = m00 * w3p00;
            acc2 = __builtin_elementwise_fma(m01, w3p01, acc2);
            acc2 = __builtin_elementwise_fma(m10, w3p10, acc2);
            acc2 = __builtin_elementwise_fma(m11, w3p11, acc2);
            float s = acc2.x + acc2.y;

            s += __shfl_xor(s, 16);
            s += __shfl_xor(s, 32);
            s += b3s;

            // swizzled store: col low-6 bits (t*16+m15) -> (m15*4+t)
            if (quad == t)
                biasb[(size_t)pix0 + m15 * 4 + t] = f2bf(s);
        }
    }
}

// ---------------------------------------------------------------------------
// Flash attention, in-block key-split; bias read as contiguous ushort4 per
// row per k-tile (biasb stored swizzled by rpb).
// ---------------------------------------------------------------------------
__global__ __launch_bounds__(512, 4) void attn_kernel(const unsigned short* __restrict__ qkv,
                                                      const unsigned short* __restrict__ biasb,
                                                      unsigned short* __restrict__ attn_out) {
    const int h = blockIdx.x;
    const int q0 = blockIdx.y * 64;
    __shared__ __align__(16) unsigned short Kst[2][64 * 72];
    __shared__ __align__(16) unsigned short Vst[2][64 * 72];  // [d][key]
    __shared__ __align__(16) unsigned short Ps[8][16 * 72];   // wave-private

    const int tid = threadIdx.x;
    const int g = tid >> 8;
    const int w = (tid >> 6) & 3;
    const int lane = tid & 63;
    const int ltid = tid & 255;
    const int m15 = lane & 15;
    const int quad = lane >> 4;

    bf16x8 qf[2];
#pragma unroll
    for (int kh = 0; kh < 2; kh++)
        qf[kh] = *reinterpret_cast<const bf16x8*>(
            qkv + (size_t)(q0 + w * 16 + m15) * 3072 + h * 64 + kh * 32 + quad * 8);

    const int kr0 = ltid >> 3, kd0 = (ltid & 7) * 8;
    const int ka = (ltid & 31) * 2;
    const int vd0 = (ltid >> 5) * 8;

    unsigned short* Kc = Kst[g];
    unsigned short* Vc = Vst[g];
    const size_t kofs = (size_t)g * 1024;

    uint4 kreg0 = *reinterpret_cast<const uint4*>(qkv + (kofs + kr0) * 3072 + 1024 + h * 64 + kd0);
    uint4 kreg1 = *reinterpret_cast<const uint4*>(qkv + (kofs + kr0 + 32) * 3072 + 1024 + h * 64 + kd0);
    uint4 vrega = *reinterpret_cast<const uint4*>(qkv + (kofs + ka) * 3072 + 2048 + h * 64 + vd0);
    uint4 vregb = *reinterpret_cast<const uint4*>(qkv + (kofs + ka + 1) * 3072 + 2048 + h * 64 + vd0);

    unsigned short br[16];
#pragma unroll
    for (int i = 0; i < 4; i++) {
        ushort4 t = *reinterpret_cast<const ushort4*>(
            biasb + (size_t)(q0 + w * 16 + quad * 4 + i) * 2048 + kofs + m15 * 4);
        br[0 * 4 + i] = t.x; br[1 * 4 + i] = t.y; br[2 * 4 + i] = t.z; br[3 * 4 + i] = t.w;
    }

    float rs[4] = {0.f, 0.f, 0.f, 0.f};
    floatx4 acc[4];
#pragma unroll
    for (int i = 0; i < 4; i++) acc[i] = {0.f, 0.f, 0.f, 0.f};
    const float c1 = 0.125f * 1.44269504f;

    for (int kt = 0; kt < 16; ++kt) {
        __syncthreads();

        *reinterpret_cast<uint4*>(&Kc[kr0 * 72 + kd0]) = kreg0;
        *reinterpret_cast<uint4*>(&Kc[(kr0 + 32) * 72 + kd0]) = kreg1;
        {
            const unsigned int* aw = reinterpret_cast<const unsigned int*>(&vrega);
            const unsigned int* bw = reinterpret_cast<const unsigned int*>(&vregb);
#pragma unroll
            for (int wd = 0; wd < 4; wd++) {
                unsigned int lo = __builtin_amdgcn_perm(bw[wd], aw[wd], 0x05040100u);
                unsigned int hi = __builtin_amdgcn_perm(bw[wd], aw[wd], 0x07060302u);
                *reinterpret_cast<unsigned int*>(&Vc[(vd0 + 2 * wd) * 72 + ka]) = lo;
                *reinterpret_cast<unsigned int*>(&Vc[(vd0 + 2 * wd + 1) * 72 + ka]) = hi;
            }
        }
        __syncthreads();

        if (kt < 15) {
            const size_t kb = kofs + (size_t)(kt + 1) * 64;
            kreg0 = *reinterpret_cast<const uint4*>(qkv + (kb + kr0) * 3072 + 1024 + h * 64 + kd0);
            kreg1 = *reinterpret_cast<const uint4*>(qkv + (kb + kr0 + 32) * 3072 + 1024 + h * 64 + kd0);
            vrega = *reinterpret_cast<const uint4*>(qkv + (kb + ka) * 3072 + 2048 + h * 64 + vd0);
            vregb = *reinterpret_cast<const uint4*>(qkv + (kb + ka + 1) * 3072 + 2048 + h * 64 + vd0);
        }

        floatx4 s[4];
#pragma unroll
        for (int nt = 0; nt < 4; nt++) s[nt] = {0.f, 0.f, 0.f, 0.f};
#pragma unroll
        for (int kh = 0; kh < 2; kh++) {
#pragma unroll
            for (int nt = 0; nt < 4; nt++) {
                bf16x8 b = *reinterpret_cast<bf16x8*>(&Kc[(nt * 16 + m15) * 72 + kh * 32 + quad * 8]);
                s[nt] = __builtin_amdgcn_mfma_f32_16x16x32_bf16(qf[kh], b, s[nt], 0, 0, 0);
            }
        }

        float p[4][4];
#pragma unroll
        for (int nt = 0; nt < 4; nt++)
#pragma unroll
            for (int i = 0; i < 4; i++) {
                float lg = fmaf(s[nt][i], c1, bf2f(br[nt * 4 + i]));
                p[nt][i] = __builtin_amdgcn_exp2f(lg);
                rs[i] += p[nt][i];
            }

        if (kt < 15) {
            const size_t kb = kofs + (size_t)(kt + 1) * 64;
#pragma unroll
            for (int i = 0; i < 4; i++) {
                ushort4 t = *reinterpret_cast<const ushort4*>(
                    biasb + (size_t)(q0 + w * 16 + quad * 4 + i) * 2048 + kb + m15 * 4);
                br[0 * 4 + i] = t.x; br[1 * 4 + i] = t.y; br[2 * 4 + i] = t.z; br[3 * 4 + i] = t.w;
            }
        }

        unsigned short* Pw = Ps[tid >> 6];
#pragma unroll
        for (int nt = 0; nt < 4; nt++)
#pragma unroll
            for (int i = 0; i < 4; i++)
                Pw[(quad * 4 + i) * 72 + nt * 16 + m15] = f2bf(p[nt][i]);
        __asm__ volatile("s_waitcnt lgkmcnt(0)" ::: "memory");

#pragma unroll
        for (int kh = 0; kh < 2; kh++) {
            bf16x8 a = *reinterpret_cast<bf16x8*>(&Pw[m15 * 72 + kh * 32 + quad * 8]);
#pragma unroll
            for (int nt = 0; nt < 4; nt++) {
                bf16x8 b = *reinterpret_cast<bf16x8*>(&Vc[(nt * 16 + m15) * 72 + kh * 32 + quad * 8]);
                acc[nt] = __builtin_amdgcn_mfma_f32_16x16x32_bf16(a, b, acc[nt], 0, 0, 0);
            }
        }
    }

    float rsum[4];
#pragma unroll
    for (int i = 0; i < 4; i++) {
        float r = rs[i];
        r += __shfl_xor(r, 1);
        r += __shfl_xor(r, 2);
        r += __shfl_xor(r, 4);
        r += __shfl_xor(r, 8);
        rsum[i] = r;
    }

    float* accbuf = reinterpret_cast<float*>(&Kst[0][0]);
    float* lbuf = accbuf + 4096;

    __syncthreads();
    if (g == 1) {
#pragma unroll
        for (int nt = 0; nt < 4; nt++)
#pragma unroll
            for (int i = 0; i < 4; i++)
                accbuf[(w * 16 + quad * 4 + i) * 64 + nt * 16 + m15] = acc[nt][i];
        if (m15 == 0) {
#pragma unroll
            for (int i = 0; i < 4; i++) lbuf[w * 16 + quad * 4 + i] = rsum[i];
        }
    }
    __syncthreads();
    if (g == 0) {
        float linv[4];
#pragma unroll
        for (int i = 0; i < 4; i++)
            linv[i] = 1.f / (rsum[i] + lbuf[w * 16 + quad * 4 + i]);
#pragma unroll
        for (int nt = 0; nt < 4; nt++)
#pragma unroll
            for (int i = 0; i < 4; i++) {
                float o = (acc[nt][i] + accbuf[(w * 16 + quad * 4 + i) * 64 + nt * 16 + m15]) * linv[i];
                int row = q0 + w * 16 + quad * 4 + i;
                int col = h * 64 + nt * 16 + m15;
                attn_out[(size_t)row * 1024 + col] = f2bf(o);
            }
    }
}

extern "C" void kernel_launch(void* const* d_in, const int* in_sizes, int n_in,
                              void* d_out, int out_size, void* d_ws, size_t ws_size,
                              hipStream_t stream) {
    const float* x      = (const float*)d_in[0];
    const float* rel    = (const float*)d_in[1];
    const float* w_qkv  = (const float*)d_in[2];
    const float* w_proj = (const float*)d_in[3];
    const float* w1     = (const float*)d_in[4];
    const float* b1     = (const float*)d_in[5];
    const float* w2     = (const float*)d_in[6];
    const float* b2     = (const float*)d_in[7];
    const float* w3     = (const float*)d_in[8];
    const float* b3     = (const float*)d_in[9];

    char* ws = (char*)d_ws;
    unsigned short* qkv   = (unsigned short*)ws;                   // 12,582,912 B
    unsigned short* biasb = (unsigned short*)(ws + 12582912);      //  8,388,608 B (bf16, *log2e, swizzled)
    unsigned short* xb    = (unsigned short*)(ws + 20971520);      //  4,194,304 B (aliased with attn)
    unsigned short* attn  = xb;                                    //  xb dead after qkv GEMM
    unsigned short* wqT   = (unsigned short*)(ws + 25165824);      //  6,291,456 B
    unsigned short* wpT   = (unsigned short*)(ws + 31457280);      //  2,097,152 B  (= 32 MiB total)
    float* out = (float*)d_out;

    prep<<<5120, 256, 0, stream>>>(x, xb, w_qkv, wqT, w_proj, wpT);
    // qkv = x @ w_qkv : m97-style 128x128 tile (384 blocks)
    gemm128<<<dim3(24, 16), 256, 0, stream>>>(xb, wqT, qkv, 2048, 3072, 1024);
    rpb_mfma_kernel<<<4096, 256, 0, stream>>>(rel, w1, b1, w2, b2, w3, b3, biasb);
    attn_kernel<<<dim3(16, 32), 512, 0, stream>>>(qkv, biasb, attn);
    gemm_abt<64, float><<<dim3(16, 32), 256, 0, stream>>>(attn, wpT, out, 2048, 1024, 1024);
}

// Round 9
// 212.980 us; speedup vs baseline: 1.0894x; 1.0894x over previous
//
#include <hip/hip_runtime.h>
#include <hip/hip_bf16.h>
#include <type_traits>

typedef __attribute__((ext_vector_type(8))) short bf16x8;
typedef __attribute__((ext_vector_type(4))) float floatx4;
typedef __attribute__((ext_vector_type(2))) float float2v;

__device__ __forceinline__ float bf2f(unsigned short u) {
    union { unsigned int x; float f; } v; v.x = ((unsigned int)u) << 16; return v.f;
}
__device__ __forceinline__ unsigned short f2bf(float f) {
    union { float f; unsigned int u; } v; v.f = f;
    unsigned int x = v.u;
    unsigned int r = x + 0x7fffu + ((x >> 16) & 1u);
    return (unsigned short)(r >> 16);
}

// async global->LDS, 16B per lane; lds base must be wave-uniform (HW adds lane*16)
typedef const __attribute__((address_space(1))) unsigned int u32_g;
typedef __attribute__((address_space(3))) unsigned int u32_l;
__device__ __forceinline__ void gld_lds16(const void* g, void* l) {
    __builtin_amdgcn_global_load_lds((u32_g*)g, (u32_l*)l, 16, 0, 0);
}

// ---------------------------------------------------------------------------
// prep: fused  x->bf16 convert  +  w_qkv^T->bf16  +  w_proj^T->bf16
// ---------------------------------------------------------------------------
__device__ __forceinline__ void trans32(const float* __restrict__ in,
                                        unsigned short* __restrict__ out,
                                        int K, int N, int bx, int by,
                                        unsigned short (*T)[33]) {
    const int n0 = bx * 32, k0 = by * 32;
    const int r = threadIdx.x >> 3;
    const int c4 = (threadIdx.x & 7) * 4;
    float4 v = *reinterpret_cast<const float4*>(in + (size_t)(k0 + r) * N + n0 + c4);
    T[c4 + 0][r] = f2bf(v.x);
    T[c4 + 1][r] = f2bf(v.y);
    T[c4 + 2][r] = f2bf(v.z);
    T[c4 + 3][r] = f2bf(v.w);
    __syncthreads();
    ushort4 o = {T[r][c4], T[r][c4 + 1], T[r][c4 + 2], T[r][c4 + 3]};
    *reinterpret_cast<ushort4*>(out + (size_t)(n0 + r) * K + k0 + c4) = o;
}

__global__ __launch_bounds__(256) void prep(const float* __restrict__ x,
                                            unsigned short* __restrict__ xb,
                                            const float* __restrict__ wq,
                                            unsigned short* __restrict__ wqT,
                                            const float* __restrict__ wp,
                                            unsigned short* __restrict__ wpT) {
    __shared__ unsigned short T[32][33];
    const int b = blockIdx.x;
    if (b < 1024) {
        size_t i = ((size_t)b * 256 + threadIdx.x) * 8;
        float4 a = *reinterpret_cast<const float4*>(x + i);
        float4 c = *reinterpret_cast<const float4*>(x + i + 4);
        unsigned short t[8] = {f2bf(a.x), f2bf(a.y), f2bf(a.z), f2bf(a.w),
                               f2bf(c.x), f2bf(c.y), f2bf(c.z), f2bf(c.w)};
        *reinterpret_cast<uint4*>(xb + i) = *reinterpret_cast<const uint4*>(t);
    } else if (b < 4096) {
        int t = b - 1024;
        trans32(wq, wqT, 1024, 3072, t % 96, t / 96, T);
    } else {
        int t = b - 4096;
        trans32(wp, wpT, 1024, 1024, t % 32, t / 32, T);
    }
}

// ---------------------------------------------------------------------------
// gemm128 body (m97-style 128x128, BK=32): qkv = xb[2048,1024] x wqT[3072,1024]^T
// ---------------------------------------------------------------------------
__device__ __forceinline__ void gemm128_body(const unsigned short* __restrict__ A,
                                             const unsigned short* __restrict__ Bt,
                                             unsigned short* __restrict__ C,
                                             int bx, int by,
                                             unsigned short* As, unsigned short* Bs) {
    const int tid = threadIdx.x;
    const int wave = tid >> 6;
    const int lane = tid & 63;
    const int m15 = lane & 15;
    const int quad = lane >> 4;
    const int wm = wave >> 1;
    const int wn = wave & 1;
    const int m0 = by * 128;
    const int n0 = bx * 128;
    const int srow = lane >> 2;
    const int scol = (lane & 3) * 8;

    floatx4 acc[4][4];
#pragma unroll
    for (int mt = 0; mt < 4; mt++)
#pragma unroll
        for (int nt = 0; nt < 4; nt++) acc[mt][nt] = {0.f, 0.f, 0.f, 0.f};

    for (int k0 = 0; k0 < 1024; k0 += 32) {
#pragma unroll
        for (int i = 0; i < 2; i++) {
            int j = wave * 2 + i;
            gld_lds16(A + (size_t)(m0 + j * 16 + srow) * 1024 + k0 + scol, &As[j * 16 * 32]);
            gld_lds16(Bt + (size_t)(n0 + j * 16 + srow) * 1024 + k0 + scol, &Bs[j * 16 * 32]);
        }
        __syncthreads();

        bf16x8 a[4];
#pragma unroll
        for (int mt = 0; mt < 4; mt++)
            a[mt] = *reinterpret_cast<bf16x8*>(&As[(wm * 64 + mt * 16 + m15) * 32 + quad * 8]);
#pragma unroll
        for (int nt = 0; nt < 4; nt++) {
            bf16x8 b = *reinterpret_cast<bf16x8*>(&Bs[(wn * 64 + nt * 16 + m15) * 32 + quad * 8]);
#pragma unroll
            for (int mt = 0; mt < 4; mt++)
                acc[mt][nt] = __builtin_amdgcn_mfma_f32_16x16x32_bf16(a[mt], b, acc[mt][nt], 0, 0, 0);
        }
        __syncthreads();
    }

#pragma unroll
    for (int mt = 0; mt < 4; mt++)
#pragma unroll
        for (int nt = 0; nt < 4; nt++)
#pragma unroll
            for (int i = 0; i < 4; i++) {
                int row = m0 + wm * 64 + mt * 16 + quad * 4 + i;
                int col = n0 + wn * 64 + nt * 16 + m15;
                C[(size_t)row * 3072 + col] = f2bf(acc[mt][nt][i]);
            }
}

// ---------------------------------------------------------------------------
// RelPosBias body, v4: operand-swapped layer-2 MFMA (zero LDS), cross-quad
// sum via a third MFMA (A=ones, B={s,0..0}, C=b3s broadcast) instead of two
// serialized shuffles; rel software-prefetched one it ahead.
// biasb stored swizzled: idx = row*2048 + (col&~63) + (col&15)*4 + ((col>>4)&3)
// Output = (mlp(rel)+b3)*log2(e) as bf16.
// ---------------------------------------------------------------------------
__device__ __forceinline__ void rpb_body(int bx,
                                         const float* __restrict__ rel,
                                         const float* __restrict__ w1,
                                         const float* __restrict__ b1,
                                         const float* __restrict__ w2,
                                         const float* __restrict__ b2,
                                         const float* __restrict__ w3,
                                         const float* __restrict__ b3,
                                         unsigned short* __restrict__ biasb) {
    const int tid = threadIdx.x;
    const int wave = tid >> 6;
    const int lane = tid & 63;
    const int m15 = lane & 15;
    const int quad = lane >> 4;

    // w2^T A-frags: lane holds A[oc=m15][ic=quad*8+j] (and oc=16+m15)
    bf16x8 af0, af1;
    {
        unsigned short t0[8], t1[8];
#pragma unroll
        for (int j = 0; j < 8; j++) {
            int k = quad * 8 + j;
            t0[j] = f2bf(w2[k * 32 + m15]);
            t1[j] = f2bf(w2[k * 32 + 16 + m15]);
        }
        af0 = *reinterpret_cast<bf16x8*>(t0);
        af1 = *reinterpret_cast<bf16x8*>(t1);
    }

    float2v w1a2[4], w1b2[4], b12[4];
#pragma unroll
    for (int p = 0; p < 4; p++) {
        int base = quad * 8 + 2 * p;
        w1a2[p] = {w1[base], w1[base + 1]};
        w1b2[p] = {w1[32 + base], w1[32 + base + 1]};
        b12[p]  = {b1[base], b1[base + 1]};
    }

    floatx4 b2r0, b2r1;
    float2v w3p00, w3p01, w3p10, w3p11;
    const float LOG2E = 1.44269504f;
    {
        float4 t0 = *reinterpret_cast<const float4*>(b2 + quad * 4);
        float4 t1 = *reinterpret_cast<const float4*>(b2 + 16 + quad * 4);
        b2r0 = {t0.x, t0.y, t0.z, t0.w};
        b2r1 = {t1.x, t1.y, t1.z, t1.w};
        float4 u0 = *reinterpret_cast<const float4*>(w3 + quad * 4);
        float4 u1 = *reinterpret_cast<const float4*>(w3 + 16 + quad * 4);
        w3p00 = {u0.x * LOG2E, u0.y * LOG2E};
        w3p01 = {u0.z * LOG2E, u0.w * LOG2E};
        w3p10 = {u1.x * LOG2E, u1.y * LOG2E};
        w3p11 = {u1.z * LOG2E, u1.w * LOG2E};
    }
    const float b3s = b3[0] * LOG2E;
    const float2v z2 = {0.f, 0.f};
    const floatx4 b3r = {b3s, b3s, b3s, b3s};

    // all-ones A-frag for the cross-quad sum MFMA
    bf16x8 ones;
    {
        unsigned int t[4] = {0x3f803f80u, 0x3f803f80u, 0x3f803f80u, 0x3f803f80u};
        ones = *reinterpret_cast<bf16x8*>(t);
    }

    const int base = bx * 1024 + wave * 64;

    float2 cur[4];
#pragma unroll
    for (int t = 0; t < 4; t++)
        cur[t] = *reinterpret_cast<const float2*>(rel + (size_t)(base + t * 16 + m15) * 2);

    for (int it = 0; it < 4; ++it) {
        const int pix0 = base + it * 256;
        float2 nxt[4];
        if (it < 3) {
#pragma unroll
            for (int t = 0; t < 4; t++)
                nxt[t] = *reinterpret_cast<const float2*>(rel + (size_t)(pix0 + 256 + t * 16 + m15) * 2);
        }

#pragma unroll
        for (int t = 0; t < 4; t++) {
            float2v dx2 = {cur[t].x, cur[t].x}, dy2 = {cur[t].y, cur[t].y};

            // layer 1: this lane's 8 channels of pixel pix0+t*16+m15
            unsigned int hp[4];
#pragma unroll
            for (int p = 0; p < 4; p++) {
                float2v h = __builtin_elementwise_fma(dx2, w1a2[p],
                             __builtin_elementwise_fma(dy2, w1b2[p], b12[p]));
                h = __builtin_elementwise_max(h, z2);
                hp[p] = __builtin_amdgcn_perm(__float_as_uint(h.y), __float_as_uint(h.x), 0x07060302u);
            }
            bf16x8 hb = *reinterpret_cast<bf16x8*>(hp);

            // layer 2: D[oc][px]
            floatx4 d0 = __builtin_amdgcn_mfma_f32_16x16x32_bf16(af0, hb, b2r0, 0, 0, 0);
            floatx4 d1 = __builtin_amdgcn_mfma_f32_16x16x32_bf16(af1, hb, b2r1, 0, 0, 0);

            // layer 3 partial: this lane's 8 oc, w3 pre-scaled by log2e
            float2v m00 = __builtin_elementwise_max(__builtin_shufflevector(d0, d0, 0, 1), z2);
            float2v m01 = __builtin_elementwise_max(__builtin_shufflevector(d0, d0, 2, 3), z2);
            float2v m10 = __builtin_elementwise_max(__builtin_shufflevector(d1, d1, 0, 1), z2);
            float2v m11 = __builtin_elementwise_max(__builtin_shufflevector(d1, d1, 2, 3), z2);
            float2v acc2 = m00 * w3p00;
            acc2 = __builtin_elementwise_fma(m01, w3p01, acc2);
            acc2 = __builtin_elementwise_fma(m10, w3p10, acc2);
            acc2 = __builtin_elementwise_fma(m11, w3p11, acc2);
            float s = acc2.x + acc2.y;

            // cross-quad sum via MFMA: B[k=quad*8+0][px=m15] = s, rest 0
            unsigned int sb[4];
            sb[0] = (unsigned int)f2bf(s);
            sb[1] = 0; sb[2] = 0; sb[3] = 0;
            bf16x8 sf = *reinterpret_cast<bf16x8*>(sb);
            floatx4 dsum = __builtin_amdgcn_mfma_f32_16x16x32_bf16(ones, sf, b3r, 0, 0, 0);

            // swizzled store (one quad per t)
            if (quad == t)
                biasb[(size_t)pix0 + m15 * 4 + t] = f2bf(dsum[0]);
        }

        if (it < 3) {
#pragma unroll
            for (int t = 0; t < 4; t++) cur[t] = nxt[t];
        }
    }
}

// ---------------------------------------------------------------------------
// Fused dispatch: blocks [0,384) = qkv GEMM (resident first), [384,4480) = rpb.
// Independent data; complementary pipes (MFMA/LDS vs VALU).
// ---------------------------------------------------------------------------
__global__ __launch_bounds__(256) void gemm_rpb(const unsigned short* __restrict__ xb,
                                                const unsigned short* __restrict__ wqT,
                                                unsigned short* __restrict__ qkv,
                                                const float* __restrict__ rel,
                                                const float* __restrict__ w1,
                                                const float* __restrict__ b1,
                                                const float* __restrict__ w2,
                                                const float* __restrict__ b2,
                                                const float* __restrict__ w3,
                                                const float* __restrict__ b3,
                                                unsigned short* __restrict__ biasb) {
    __shared__ __align__(16) unsigned short S[2 * 128 * 32];
    const int b = blockIdx.x;
    if (b < 384)
        gemm128_body(xb, wqT, qkv, b % 24, b / 24, S, S + 128 * 32);
    else
        rpb_body(b - 384, rel, w1, b1, w2, b2, w3, b3, biasb);
}

// ---------------------------------------------------------------------------
// GEMM: BM=64 (used for proj). C fp32 out.
// ---------------------------------------------------------------------------
template<int BN, typename TC>
__global__ __launch_bounds__(256) void gemm_abt(const unsigned short* __restrict__ A,
                                                const unsigned short* __restrict__ Bt,
                                                TC* __restrict__ C,
                                                int M, int N, int K) {
    constexpr int NT = BN / 32;
    __shared__ __align__(16) unsigned short As[64 * 32];
    __shared__ __align__(16) unsigned short Bs[BN * 32];

    const int tid = threadIdx.x;
    const int wave = tid >> 6;
    const int lane = tid & 63;
    const int m15 = lane & 15;
    const int quad = lane >> 4;
    const int wm = wave >> 1;
    const int wn = wave & 1;
    const int m0 = blockIdx.y * 64;
    const int n0 = blockIdx.x * BN;

    const int srow = lane >> 2;
    const int scol = (lane & 3) * 8;

    floatx4 acc[2][NT];
#pragma unroll
    for (int mt = 0; mt < 2; mt++)
#pragma unroll
        for (int nt = 0; nt < NT; nt++) acc[mt][nt] = {0.f, 0.f, 0.f, 0.f};

    for (int k0 = 0; k0 < K; k0 += 32) {
        gld_lds16(A + (size_t)(m0 + wave * 16 + srow) * K + k0 + scol, &As[wave * 16 * 32]);
#pragma unroll
        for (int i = 0; i < BN / 64; i++) {
            int j = wave * (BN / 64) + i;
            gld_lds16(Bt + (size_t)(n0 + j * 16 + srow) * K + k0 + scol, &Bs[j * 16 * 32]);
        }
        __syncthreads();

        bf16x8 a[2];
#pragma unroll
        for (int mt = 0; mt < 2; mt++)
            a[mt] = *reinterpret_cast<bf16x8*>(&As[(wm * 32 + mt * 16 + m15) * 32 + quad * 8]);
#pragma unroll
        for (int nt = 0; nt < NT; nt++) {
            bf16x8 b = *reinterpret_cast<bf16x8*>(&Bs[(wn * (BN / 2) + nt * 16 + m15) * 32 + quad * 8]);
#pragma unroll
            for (int mt = 0; mt < 2; mt++)
                acc[mt][nt] = __builtin_amdgcn_mfma_f32_16x16x32_bf16(a[mt], b, acc[mt][nt], 0, 0, 0);
        }
        __syncthreads();
    }

#pragma unroll
    for (int mt = 0; mt < 2; mt++)
#pragma unroll
        for (int nt = 0; nt < NT; nt++)
#pragma unroll
            for (int i = 0; i < 4; i++) {
                int row = m0 + wm * 32 + mt * 16 + quad * 4 + i;
                int col = n0 + wn * (BN / 2) + nt * 16 + m15;
                if constexpr (std::is_same<TC, float>::value)
                    C[(size_t)row * N + col] = acc[mt][nt][i];
                else
                    C[(size_t)row * N + col] = f2bf(acc[mt][nt][i]);
            }
}

// ---------------------------------------------------------------------------
// Flash attention, in-block key-split; bias read as contiguous ushort4 per
// row per k-tile (biasb stored swizzled by rpb).
// ---------------------------------------------------------------------------
__global__ __launch_bounds__(512, 4) void attn_kernel(const unsigned short* __restrict__ qkv,
                                                      const unsigned short* __restrict__ biasb,
                                                      unsigned short* __restrict__ attn_out) {
    const int h = blockIdx.x;
    const int q0 = blockIdx.y * 64;
    __shared__ __align__(16) unsigned short Kst[2][64 * 72];
    __shared__ __align__(16) unsigned short Vst[2][64 * 72];  // [d][key]
    __shared__ __align__(16) unsigned short Ps[8][16 * 72];   // wave-private

    const int tid = threadIdx.x;
    const int g = tid >> 8;
    const int w = (tid >> 6) & 3;
    const int lane = tid & 63;
    const int ltid = tid & 255;
    const int m15 = lane & 15;
    const int quad = lane >> 4;

    bf16x8 qf[2];
#pragma unroll
    for (int kh = 0; kh < 2; kh++)
        qf[kh] = *reinterpret_cast<const bf16x8*>(
            qkv + (size_t)(q0 + w * 16 + m15) * 3072 + h * 64 + kh * 32 + quad * 8);

    const int kr0 = ltid >> 3, kd0 = (ltid & 7) * 8;
    const int ka = (ltid & 31) * 2;
    const int vd0 = (ltid >> 5) * 8;

    unsigned short* Kc = Kst[g];
    unsigned short* Vc = Vst[g];
    const size_t kofs = (size_t)g * 1024;

    uint4 kreg0 = *reinterpret_cast<const uint4*>(qkv + (kofs + kr0) * 3072 + 1024 + h * 64 + kd0);
    uint4 kreg1 = *reinterpret_cast<const uint4*>(qkv + (kofs + kr0 + 32) * 3072 + 1024 + h * 64 + kd0);
    uint4 vrega = *reinterpret_cast<const uint4*>(qkv + (kofs + ka) * 3072 + 2048 + h * 64 + vd0);
    uint4 vregb = *reinterpret_cast<const uint4*>(qkv + (kofs + ka + 1) * 3072 + 2048 + h * 64 + vd0);

    unsigned short br[16];
#pragma unroll
    for (int i = 0; i < 4; i++) {
        ushort4 t = *reinterpret_cast<const ushort4*>(
            biasb + (size_t)(q0 + w * 16 + quad * 4 + i) * 2048 + kofs + m15 * 4);
        br[0 * 4 + i] = t.x; br[1 * 4 + i] = t.y; br[2 * 4 + i] = t.z; br[3 * 4 + i] = t.w;
    }

    float rs[4] = {0.f, 0.f, 0.f, 0.f};
    floatx4 acc[4];
#pragma unroll
    for (int i = 0; i < 4; i++) acc[i] = {0.f, 0.f, 0.f, 0.f};
    const float c1 = 0.125f * 1.44269504f;

    for (int kt = 0; kt < 16; ++kt) {
        __syncthreads();

        *reinterpret_cast<uint4*>(&Kc[kr0 * 72 + kd0]) = kreg0;
        *reinterpret_cast<uint4*>(&Kc[(kr0 + 32) * 72 + kd0]) = kreg1;
        {
            const unsigned int* aw = reinterpret_cast<const unsigned int*>(&vrega);
            const unsigned int* bw = reinterpret_cast<const unsigned int*>(&vregb);
#pragma unroll
            for (int wd = 0; wd < 4; wd++) {
                unsigned int lo = __builtin_amdgcn_perm(bw[wd], aw[wd], 0x05040100u);
                unsigned int hi = __builtin_amdgcn_perm(bw[wd], aw[wd], 0x07060302u);
                *reinterpret_cast<unsigned int*>(&Vc[(vd0 + 2 * wd) * 72 + ka]) = lo;
                *reinterpret_cast<unsigned int*>(&Vc[(vd0 + 2 * wd + 1) * 72 + ka]) = hi;
            }
        }
        __syncthreads();

        if (kt < 15) {
            const size_t kb = kofs + (size_t)(kt + 1) * 64;
            kreg0 = *reinterpret_cast<const uint4*>(qkv + (kb + kr0) * 3072 + 1024 + h * 64 + kd0);
            kreg1 = *reinterpret_cast<const uint4*>(qkv + (kb + kr0 + 32) * 3072 + 1024 + h * 64 + kd0);
            vrega = *reinterpret_cast<const uint4*>(qkv + (kb + ka) * 3072 + 2048 + h * 64 + vd0);
            vregb = *reinterpret_cast<const uint4*>(qkv + (kb + ka + 1) * 3072 + 2048 + h * 64 + vd0);
        }

        floatx4 s[4];
#pragma unroll
        for (int nt = 0; nt < 4; nt++) s[nt] = {0.f, 0.f, 0.f, 0.f};
#pragma unroll
        for (int kh = 0; kh < 2; kh++) {
#pragma unroll
            for (int nt = 0; nt < 4; nt++) {
                bf16x8 b = *reinterpret_cast<bf16x8*>(&Kc[(nt * 16 + m15) * 72 + kh * 32 + quad * 8]);
                s[nt] = __builtin_amdgcn_mfma_f32_16x16x32_bf16(qf[kh], b, s[nt], 0, 0, 0);
            }
        }

        float p[4][4];
#pragma unroll
        for (int nt = 0; nt < 4; nt++)
#pragma unroll
            for (int i = 0; i < 4; i++) {
                float lg = fmaf(s[nt][i], c1, bf2f(br[nt * 4 + i]));
                p[nt][i] = __builtin_amdgcn_exp2f(lg);
                rs[i] += p[nt][i];
            }

        if (kt < 15) {
            const size_t kb = kofs + (size_t)(kt + 1) * 64;
#pragma unroll
            for (int i = 0; i < 4; i++) {
                ushort4 t = *reinterpret_cast<const ushort4*>(
                    biasb + (size_t)(q0 + w * 16 + quad * 4 + i) * 2048 + kb + m15 * 4);
                br[0 * 4 + i] = t.x; br[1 * 4 + i] = t.y; br[2 * 4 + i] = t.z; br[3 * 4 + i] = t.w;
            }
        }

        unsigned short* Pw = Ps[tid >> 6];
#pragma unroll
        for (int nt = 0; nt < 4; nt++)
#pragma unroll
            for (int i = 0; i < 4; i++)
                Pw[(quad * 4 + i) * 72 + nt * 16 + m15] = f2bf(p[nt][i]);
        __asm__ volatile("s_waitcnt lgkmcnt(0)" ::: "memory");

#pragma unroll
        for (int kh = 0; kh < 2; kh++) {
            bf16x8 a = *reinterpret_cast<bf16x8*>(&Pw[m15 * 72 + kh * 32 + quad * 8]);
#pragma unroll
            for (int nt = 0; nt < 4; nt++) {
                bf16x8 b = *reinterpret_cast<bf16x8*>(&Vc[(nt * 16 + m15) * 72 + kh * 32 + quad * 8]);
                acc[nt] = __builtin_amdgcn_mfma_f32_16x16x32_bf16(a, b, acc[nt], 0, 0, 0);
            }
        }
    }

    float rsum[4];
#pragma unroll
    for (int i = 0; i < 4; i++) {
        float r = rs[i];
        r += __shfl_xor(r, 1);
        r += __shfl_xor(r, 2);
        r += __shfl_xor(r, 4);
        r += __shfl_xor(r, 8);
        rsum[i] = r;
    }

    float* accbuf = reinterpret_cast<float*>(&Kst[0][0]);
    float* lbuf = accbuf + 4096;

    __syncthreads();
    if (g == 1) {
#pragma unroll
        for (int nt = 0; nt < 4; nt++)
#pragma unroll
            for (int i = 0; i < 4; i++)
                accbuf[(w * 16 + quad * 4 + i) * 64 + nt * 16 + m15] = acc[nt][i];
        if (m15 == 0) {
#pragma unroll
            for (int i = 0; i < 4; i++) lbuf[w * 16 + quad * 4 + i] = rsum[i];
        }
    }
    __syncthreads();
    if (g == 0) {
        float linv[4];
#pragma unroll
        for (int i = 0; i < 4; i++)
            linv[i] = 1.f / (rsum[i] + lbuf[w * 16 + quad * 4 + i]);
#pragma unroll
        for (int nt = 0; nt < 4; nt++)
#pragma unroll
            for (int i = 0; i < 4; i++) {
                float o = (acc[nt][i] + accbuf[(w * 16 + quad * 4 + i) * 64 + nt * 16 + m15]) * linv[i];
                int row = q0 + w * 16 + quad * 4 + i;
                int col = h * 64 + nt * 16 + m15;
                attn_out[(size_t)row * 1024 + col] = f2bf(o);
            }
    }
}

extern "C" void kernel_launch(void* const* d_in, const int* in_sizes, int n_in,
                              void* d_out, int out_size, void* d_ws, size_t ws_size,
                              hipStream_t stream) {
    const float* x      = (const float*)d_in[0];
    const float* rel    = (const float*)d_in[1];
    const float* w_qkv  = (const float*)d_in[2];
    const float* w_proj = (const float*)d_in[3];
    const float* w1     = (const float*)d_in[4];
    const float* b1     = (const float*)d_in[5];
    const float* w2     = (const float*)d_in[6];
    const float* b2     = (const float*)d_in[7];
    const float* w3     = (const float*)d_in[8];
    const float* b3     = (const float*)d_in[9];

    char* ws = (char*)d_ws;
    unsigned short* qkv   = (unsigned short*)ws;                   // 12,582,912 B
    unsigned short* biasb = (unsigned short*)(ws + 12582912);      //  8,388,608 B (bf16, *log2e, swizzled)
    unsigned short* xb    = (unsigned short*)(ws + 20971520);      //  4,194,304 B (aliased with attn)
    unsigned short* attn  = xb;                                    //  xb dead after qkv GEMM
    unsigned short* wqT   = (unsigned short*)(ws + 25165824);      //  6,291,456 B
    unsigned short* wpT   = (unsigned short*)(ws + 31457280);      //  2,097,152 B  (= 32 MiB total)
    float* out = (float*)d_out;

    prep<<<5120, 256, 0, stream>>>(x, xb, w_qkv, wqT, w_proj, wpT);
    // fused: qkv GEMM (blocks 0-383) + RPB MLP (blocks 384-4479)
    gemm_rpb<<<4480, 256, 0, stream>>>(xb, wqT, qkv, rel, w1, b1, w2, b2, w3, b3, biasb);
    attn_kernel<<<dim3(16, 32), 512, 0, stream>>>(qkv, biasb, attn);
    gemm_abt<64, float><<<dim3(16, 32), 256, 0, stream>>>(attn, wpT, out, 2048, 1024, 1024);
}